// Round 2
// baseline (827.315 us; speedup 1.0000x reference)
//
#include <hip/hip_runtime.h>

#define THREADS 256

// Zero the first n floats of p (replaces hipMemsetAsync for graph-capture safety).
__global__ void k_zero(float* __restrict__ p, int n) {
    int i = blockIdx.x * blockDim.x + threadIdx.x;
    int v = i * 4;
    if (v + 3 < n) {
        reinterpret_cast<float4*>(p + v)[0] = make_float4(0.f, 0.f, 0.f, 0.f);
    } else {
        for (; v < n; ++v) p[v] = 0.0f;
    }
}

// Pass 1: in-degree over edges (self-loop added analytically later). 4 edges/thread.
__global__ void k_deg(const int* __restrict__ col, float* __restrict__ deg, int E) {
    int i = blockIdx.x * blockDim.x + threadIdx.x;
    int e = i * 4;
    if (e + 3 < E) {
        int4 c = reinterpret_cast<const int4*>(col + e)[0];
        atomicAdd(deg + c.x, 1.0f);
        atomicAdd(deg + c.y, 1.0f);
        atomicAdd(deg + c.z, 1.0f);
        atomicAdd(deg + c.w, 1.0f);
    } else {
        for (; e < E; ++e) atomicAdd(deg + col[e], 1.0f);
    }
}

// Per-node: dinv = rsqrt(deg+1) (self-loop), stored in place; xs = dinv*x.
__global__ void k_node1(const float* __restrict__ x, float* __restrict__ degdinv,
                        float* __restrict__ xs, int N) {
    int v = blockIdx.x * blockDim.x + threadIdx.x;
    if (v < N) {
        float dinv = rsqrtf(degdinv[v] + 1.0f);
        degdinv[v] = dinv;
        xs[v] = dinv * x[v];
    }
}

// Scatter: acc[col] += src[row]  (src pre-scaled by dinv[row]). 4 edges/thread.
__global__ void k_scat(const int* __restrict__ row, const int* __restrict__ col,
                       const float* __restrict__ src, float* __restrict__ acc, int E) {
    int i = blockIdx.x * blockDim.x + threadIdx.x;
    int e = i * 4;
    if (e + 3 < E) {
        int4 r = reinterpret_cast<const int4*>(row + e)[0];
        int4 c = reinterpret_cast<const int4*>(col + e)[0];
        float s0 = src[r.x];
        float s1 = src[r.y];
        float s2 = src[r.z];
        float s3 = src[r.w];
        atomicAdd(acc + c.x, s0);
        atomicAdd(acc + c.y, s1);
        atomicAdd(acc + c.z, s2);
        atomicAdd(acc + c.w, s3);
    } else {
        for (; e < E; ++e) atomicAdd(acc + col[e], src[row[e]]);
    }
}

// Per-node MLP between the two propagations:
//   t = dinv*(acc + xs);  g = sum_j (W2[j][0]-W2[j][1]) * relu(W1[j]*t + b1[j]);
//   xsgs <- dinv*g (source for layer-2 scatter);  acc <- 0 (reused as L2 accumulator).
__global__ void k_mlp(const float* __restrict__ W1, const float* __restrict__ b1,
                      const float* __restrict__ W2,
                      const float* __restrict__ dinv, float* __restrict__ acc,
                      float* __restrict__ xsgs, int N) {
    int v = blockIdx.x * blockDim.x + threadIdx.x;
    if (v < N) {
        float di = dinv[v];
        float t = di * (acc[v] + xsgs[v]);
        float g = 0.0f;
#pragma unroll
        for (int j = 0; j < 16; ++j) {
            float y = fmaxf(fmaf(W1[j], t, b1[j]), 0.0f);
            g = fmaf(W2[2 * j] - W2[2 * j + 1], y, g);
        }
        xsgs[v] = di * g;
        acc[v] = 0.0f;
    }
}

// Final: logit diff -> sigmoid -> (p0, 1-p0), float2 store.
__global__ void k_out(const float* __restrict__ b2, const float* __restrict__ dinv,
                      const float* __restrict__ acc, const float* __restrict__ gs,
                      float* __restrict__ out, int N) {
    int v = blockIdx.x * blockDim.x + threadIdx.x;
    if (v < N) {
        float diff = dinv[v] * (acc[v] + gs[v]) + (b2[0] - b2[1]);
        float p0 = 1.0f / (1.0f + __expf(-diff));
        float2 o;
        o.x = p0;
        o.y = 1.0f - p0;
        reinterpret_cast<float2*>(out)[v] = o;
    }
}

extern "C" void kernel_launch(void* const* d_in, const int* in_sizes, int n_in,
                              void* d_out, int out_size, void* d_ws, size_t ws_size,
                              hipStream_t stream) {
    const float* x  = (const float*)d_in[0];
    const int* edge = (const int*)d_in[1];   // int64 in reference -> int32 in harness
    const float* W1 = (const float*)d_in[2];
    const float* b1 = (const float*)d_in[3];
    const float* W2 = (const float*)d_in[4];
    const float* b2 = (const float*)d_in[5];
    float* out = (float*)d_out;

    const int N = in_sizes[0];          // x is (N,1)
    const int E = in_sizes[1] / 2;      // edge_index is (2,E)
    const int* row = edge;              // sources
    const int* col = edge + E;          // targets

    // Workspace layout (floats): [0,N) deg->dinv | [N,2N) acc | [2N,3N) xs->gs
    float* w0 = (float*)d_ws;
    float* w1 = w0 + N;
    float* w2 = w1 + N;

    const int zb  = ((2 * N + 3) / 4 + THREADS - 1) / THREADS;
    const int eb  = ((E + 3) / 4 + THREADS - 1) / THREADS;
    const int nb  = (N + THREADS - 1) / THREADS;

    k_zero <<<zb, THREADS, 0, stream>>>(w0, 2 * N);               // zero deg + acc
    k_deg  <<<eb, THREADS, 0, stream>>>(col, w0, E);
    k_node1<<<nb, THREADS, 0, stream>>>(x, w0, w2, N);
    k_scat <<<eb, THREADS, 0, stream>>>(row, col, w2, w1, E);     // layer-1 scatter
    k_mlp  <<<nb, THREADS, 0, stream>>>(W1, b1, W2, w0, w1, w2, N);
    k_scat <<<eb, THREADS, 0, stream>>>(row, col, w2, w1, E);     // layer-2 scatter
    k_out  <<<nb, THREADS, 0, stream>>>(b2, w0, w1, w2, out, N);
}

// Round 3
// 449.676 us; speedup vs baseline: 1.8398x; 1.8398x over previous
//
#include <hip/hip_runtime.h>

#define THREADS 256
// Scan geometry: chunks of 1024 ints, one 256-thread block per chunk, single
// block scans the per-chunk sums (requires nchunks <= 256, i.e. N <= 262144).
#define CHUNK 1024

// ---------------------------------------------------------------- utilities
__global__ void k_zero_i(int* __restrict__ p, int n) {
    int i = blockIdx.x * blockDim.x + threadIdx.x;
    int v = i * 4;
    if (v + 3 < n) {
        reinterpret_cast<int4*>(p + v)[0] = make_int4(0, 0, 0, 0);
    } else {
        for (; v < n; ++v) p[v] = 0;
    }
}

// ---------------------------------------------------- CSR build (one atomic pass)
// rank[e] = old count of col[e]; deg accumulates in-degree (excl self-loop).
__global__ void k_degrank(const int* __restrict__ col, int* __restrict__ deg,
                          int* __restrict__ rank, int E) {
    int i = blockIdx.x * blockDim.x + threadIdx.x;
    int e = i * 4;
    if (e + 3 < E) {
        int4 c = reinterpret_cast<const int4*>(col + e)[0];
        int4 r;
        r.x = atomicAdd(deg + c.x, 1);
        r.y = atomicAdd(deg + c.y, 1);
        r.z = atomicAdd(deg + c.z, 1);
        r.w = atomicAdd(deg + c.w, 1);
        reinterpret_cast<int4*>(rank + e)[0] = r;
    } else {
        for (; e < E; ++e) rank[e] = atomicAdd(deg + col[e], 1);
    }
}

// Per-chunk sums for the scan.
__global__ void k_chunksum(const int* __restrict__ deg, int* __restrict__ bsum, int N) {
    __shared__ int s[THREADS];
    int t = threadIdx.x;
    int base = blockIdx.x * CHUNK + t * 4;
    int acc = 0;
    for (int k = 0; k < 4; ++k) {
        int idx = base + k;
        if (idx < N) acc += deg[idx];
    }
    s[t] = acc;
    __syncthreads();
    for (int o = THREADS / 2; o > 0; o >>= 1) {
        if (t < o) s[t] += s[t + o];
        __syncthreads();
    }
    if (t == 0) bsum[blockIdx.x] = s[0];
}

// Single-block exclusive scan of per-chunk sums (nb <= 256).
__global__ void k_scanblocks(int* __restrict__ bsum, int nb) {
    __shared__ int s[THREADS];
    int t = threadIdx.x;
    int v = (t < nb) ? bsum[t] : 0;
    s[t] = v;
    __syncthreads();
    for (int o = 1; o < THREADS; o <<= 1) {
        int x = (t >= o) ? s[t - o] : 0;
        __syncthreads();
        s[t] += x;
        __syncthreads();
    }
    if (t < nb) bsum[t] = s[t] - v;  // exclusive
}

// Per-chunk exclusive scan + chunk offset -> start[].
__global__ void k_scanchunk(const int* __restrict__ deg, const int* __restrict__ bsum,
                            int* __restrict__ start, int N) {
    __shared__ int s[THREADS];
    int t = threadIdx.x;
    int base = blockIdx.x * CHUNK + t * 4;
    int v[4];
    int acc = 0;
    for (int k = 0; k < 4; ++k) {
        int idx = base + k;
        v[k] = (idx < N) ? deg[idx] : 0;
        acc += v[k];
    }
    s[t] = acc;
    __syncthreads();
    for (int o = 1; o < THREADS; o <<= 1) {
        int x = (t >= o) ? s[t - o] : 0;
        __syncthreads();
        s[t] += x;
        __syncthreads();
    }
    int off = bsum[blockIdx.x] + s[t] - acc;  // exclusive offset for this thread's 4
    for (int k = 0; k < 4; ++k) {
        int idx = base + k;
        if (idx < N) start[idx] = off;
        off += v[k];
    }
}

// Place: sortedrow[start[col] + rank] = row. Plain stores (L2 write-back).
__global__ void k_place(const int* __restrict__ row, const int* __restrict__ col,
                        const int* __restrict__ rank, const int* __restrict__ start,
                        int* __restrict__ sortedrow, int E) {
    int i = blockIdx.x * blockDim.x + threadIdx.x;
    int e = i * 4;
    if (e + 3 < E) {
        int4 r = reinterpret_cast<const int4*>(row + e)[0];
        int4 c = reinterpret_cast<const int4*>(col + e)[0];
        int4 k = reinterpret_cast<const int4*>(rank + e)[0];
        sortedrow[start[c.x] + k.x] = r.x;
        sortedrow[start[c.y] + k.y] = r.y;
        sortedrow[start[c.z] + k.z] = r.z;
        sortedrow[start[c.w] + k.w] = r.w;
    } else {
        for (; e < E; ++e) sortedrow[start[col[e]] + rank[e]] = row[e];
    }
}

// Per-node: dinv = rsqrt(deg+1) (self-loop), xs = dinv*x.
__global__ void k_node1(const float* __restrict__ x, const int* __restrict__ deg,
                        float* __restrict__ dinv, float* __restrict__ xs, int N) {
    int v = blockIdx.x * blockDim.x + threadIdx.x;
    if (v < N) {
        float di = rsqrtf((float)deg[v] + 1.0f);
        dinv[v] = di;
        xs[v] = di * x[v];
    }
}

// Gather layer 1 + fused 16-unit MLP collapse:
//   t = dinv[v]*(sum_{incoming} xs[row] + xs[v])
//   g = sum_j (W2[j][0]-W2[j][1]) * relu(W1[j]*t + b1[j]);  gs[v] = dinv[v]*g
// (gs overwrites xs' companion buffer)
__global__ void k_gather_mlp(const int* __restrict__ start, const int* __restrict__ deg,
                             const int* __restrict__ sortedrow,
                             const float* __restrict__ xs, const float* __restrict__ dinv,
                             const float* __restrict__ W1, const float* __restrict__ b1,
                             const float* __restrict__ W2,
                             float* __restrict__ gs, int N) {
    int v = blockIdx.x * blockDim.x + threadIdx.x;
    if (v < N) {
        int s0 = start[v];
        int d = deg[v];
        float s = xs[v];  // self-loop
        for (int i = 0; i < d; ++i) {
            s += xs[sortedrow[s0 + i]];
        }
        float di = dinv[v];
        float t = di * s;
        float g = 0.0f;
#pragma unroll
        for (int j = 0; j < 16; ++j) {
            float y = fmaxf(fmaf(W1[j], t, b1[j]), 0.0f);
            g = fmaf(W2[2 * j] - W2[2 * j + 1], y, g);
        }
        gs[v] = di * g;
    }
}

// Gather layer 2 + sigmoid epilogue -> (p0, 1-p0).
__global__ void k_gather_out(const int* __restrict__ start, const int* __restrict__ deg,
                             const int* __restrict__ sortedrow,
                             const float* __restrict__ gs, const float* __restrict__ dinv,
                             const float* __restrict__ b2,
                             float* __restrict__ out, int N) {
    int v = blockIdx.x * blockDim.x + threadIdx.x;
    if (v < N) {
        int s0 = start[v];
        int d = deg[v];
        float s = gs[v];  // self-loop
        for (int i = 0; i < d; ++i) {
            s += gs[sortedrow[s0 + i]];
        }
        float diff = dinv[v] * s + (b2[0] - b2[1]);
        float p0 = 1.0f / (1.0f + __expf(-diff));
        float2 o;
        o.x = p0;
        o.y = 1.0f - p0;
        reinterpret_cast<float2*>(out)[v] = o;
    }
}

// ---------------------------------------------------------------- fallback path
// (original R2 atomic-scatter version, used only if ws_size is too small for CSR)
__global__ void k_zero_f(float* __restrict__ p, int n) {
    int i = blockIdx.x * blockDim.x + threadIdx.x;
    int v = i * 4;
    if (v + 3 < n) {
        reinterpret_cast<float4*>(p + v)[0] = make_float4(0.f, 0.f, 0.f, 0.f);
    } else {
        for (; v < n; ++v) p[v] = 0.0f;
    }
}
__global__ void k_deg_f(const int* __restrict__ col, float* __restrict__ deg, int E) {
    int i = blockIdx.x * blockDim.x + threadIdx.x;
    int e = i * 4;
    if (e + 3 < E) {
        int4 c = reinterpret_cast<const int4*>(col + e)[0];
        atomicAdd(deg + c.x, 1.0f); atomicAdd(deg + c.y, 1.0f);
        atomicAdd(deg + c.z, 1.0f); atomicAdd(deg + c.w, 1.0f);
    } else {
        for (; e < E; ++e) atomicAdd(deg + col[e], 1.0f);
    }
}
__global__ void k_node1_f(const float* __restrict__ x, float* __restrict__ degdinv,
                          float* __restrict__ xs, int N) {
    int v = blockIdx.x * blockDim.x + threadIdx.x;
    if (v < N) {
        float dinv = rsqrtf(degdinv[v] + 1.0f);
        degdinv[v] = dinv;
        xs[v] = dinv * x[v];
    }
}
__global__ void k_scat_f(const int* __restrict__ row, const int* __restrict__ col,
                         const float* __restrict__ src, float* __restrict__ acc, int E) {
    int i = blockIdx.x * blockDim.x + threadIdx.x;
    int e = i * 4;
    if (e + 3 < E) {
        int4 r = reinterpret_cast<const int4*>(row + e)[0];
        int4 c = reinterpret_cast<const int4*>(col + e)[0];
        float s0 = src[r.x], s1 = src[r.y], s2 = src[r.z], s3 = src[r.w];
        atomicAdd(acc + c.x, s0); atomicAdd(acc + c.y, s1);
        atomicAdd(acc + c.z, s2); atomicAdd(acc + c.w, s3);
    } else {
        for (; e < E; ++e) atomicAdd(acc + col[e], src[row[e]]);
    }
}
__global__ void k_mlp_f(const float* __restrict__ W1, const float* __restrict__ b1,
                        const float* __restrict__ W2, const float* __restrict__ dinv,
                        float* __restrict__ acc, float* __restrict__ xsgs, int N) {
    int v = blockIdx.x * blockDim.x + threadIdx.x;
    if (v < N) {
        float di = dinv[v];
        float t = di * (acc[v] + xsgs[v]);
        float g = 0.0f;
#pragma unroll
        for (int j = 0; j < 16; ++j) {
            float y = fmaxf(fmaf(W1[j], t, b1[j]), 0.0f);
            g = fmaf(W2[2 * j] - W2[2 * j + 1], y, g);
        }
        xsgs[v] = di * g;
        acc[v] = 0.0f;
    }
}
__global__ void k_out_f(const float* __restrict__ b2, const float* __restrict__ dinv,
                        const float* __restrict__ acc, const float* __restrict__ gs,
                        float* __restrict__ out, int N) {
    int v = blockIdx.x * blockDim.x + threadIdx.x;
    if (v < N) {
        float diff = dinv[v] * (acc[v] + gs[v]) + (b2[0] - b2[1]);
        float p0 = 1.0f / (1.0f + __expf(-diff));
        float2 o; o.x = p0; o.y = 1.0f - p0;
        reinterpret_cast<float2*>(out)[v] = o;
    }
}

extern "C" void kernel_launch(void* const* d_in, const int* in_sizes, int n_in,
                              void* d_out, int out_size, void* d_ws, size_t ws_size,
                              hipStream_t stream) {
    const float* x  = (const float*)d_in[0];
    const int* edge = (const int*)d_in[1];   // int64 in reference -> int32 in harness
    const float* W1 = (const float*)d_in[2];
    const float* b1 = (const float*)d_in[3];
    const float* W2 = (const float*)d_in[4];
    const float* b2 = (const float*)d_in[5];
    float* out = (float*)d_out;

    const int N = in_sizes[0];
    const int E = in_sizes[1] / 2;
    const int* row = edge;       // sources
    const int* col = edge + E;   // targets

    const int nchunks = (N + CHUNK - 1) / CHUNK;
    const size_t need = ((size_t)2 * E + 4 * (size_t)N + THREADS) * 4 +
                        (size_t)2 * N * 4;  // ints + floats below

    const int eb = ((E + 3) / 4 + THREADS - 1) / THREADS;
    const int nb = (N + THREADS - 1) / THREADS;

    if (ws_size >= need && nchunks <= THREADS) {
        // ---- CSR gather path ----
        // ints:   rank[E] | sortedrow[E] | deg[N] | start[N] | bsum[THREADS]
        // floats: dinv[N] | xs/gs... (xs[N], gs[N])
        int* rank      = (int*)d_ws;
        int* sortedrow = rank + E;
        int* deg       = sortedrow + E;
        int* start     = deg + N;
        int* bsum      = start + N;
        float* dinv    = (float*)(bsum + THREADS);
        float* xs      = dinv + N;
        float* gs      = xs + N;   // NOTE: gs aliases nothing; xs stays live for gather1 only

        const int zb = ((N + 3) / 4 + THREADS - 1) / THREADS;

        k_zero_i    <<<zb, THREADS, 0, stream>>>(deg, N);
        k_degrank   <<<eb, THREADS, 0, stream>>>(col, deg, rank, E);
        k_chunksum  <<<nchunks, THREADS, 0, stream>>>(deg, bsum, N);
        k_scanblocks<<<1, THREADS, 0, stream>>>(bsum, nchunks);
        k_scanchunk <<<nchunks, THREADS, 0, stream>>>(deg, bsum, start, N);
        k_place     <<<eb, THREADS, 0, stream>>>(row, col, rank, start, sortedrow, E);
        k_node1     <<<nb, THREADS, 0, stream>>>(x, deg, dinv, xs, N);
        k_gather_mlp<<<nb, THREADS, 0, stream>>>(start, deg, sortedrow, xs, dinv,
                                                 W1, b1, W2, gs, N);
        k_gather_out<<<nb, THREADS, 0, stream>>>(start, deg, sortedrow, gs, dinv,
                                                 b2, out, N);
    } else {
        // ---- fallback: R2 atomic-scatter path (3N floats) ----
        float* w0 = (float*)d_ws;
        float* w1 = w0 + N;
        float* w2 = w1 + N;
        const int zb = ((2 * N + 3) / 4 + THREADS - 1) / THREADS;
        k_zero_f<<<zb, THREADS, 0, stream>>>(w0, 2 * N);
        k_deg_f <<<eb, THREADS, 0, stream>>>(col, w0, E);
        k_node1_f<<<nb, THREADS, 0, stream>>>(x, w0, w2, N);
        k_scat_f<<<eb, THREADS, 0, stream>>>(row, col, w2, w1, E);
        k_mlp_f <<<nb, THREADS, 0, stream>>>(W1, b1, W2, w0, w1, w2, N);
        k_scat_f<<<eb, THREADS, 0, stream>>>(row, col, w2, w1, E);
        k_out_f <<<nb, THREADS, 0, stream>>>(b2, w0, w1, w2, out, N);
    }
}

// Round 4
// 226.008 us; speedup vs baseline: 3.6605x; 1.9896x over previous
//
#include <hip/hip_runtime.h>

#define THREADS 256
#define EPB 10240        // edges per histogram/scatter block (40 iters of 256)
#define SCHUNK 4096      // scan chunk (256 threads x 16 items)

// ============================ bucketed-sort path ============================
// bucket = col >> 8 (width 256 nodes). packed edge = (row << 8) | (col & 255).
// Requires N < 2^24 and nbuckets <= 1024.

// Per-block bucket histogram -> H[bucket * NBH + block].
__global__ void k_hist(const int* __restrict__ col, unsigned* __restrict__ H,
                       int E, int NBH, int NBUCKETS) {
    __shared__ unsigned cnt[1024];
    for (int b = threadIdx.x; b < NBUCKETS; b += THREADS) cnt[b] = 0;
    __syncthreads();
    int base = blockIdx.x * EPB;
    int end = min(base + EPB, E);
    for (int e = base + threadIdx.x * 4; e < end; e += THREADS * 4) {
        if (e + 3 < end) {
            int4 c = reinterpret_cast<const int4*>(col + e)[0];
            atomicAdd(&cnt[(unsigned)c.x >> 8], 1u);
            atomicAdd(&cnt[(unsigned)c.y >> 8], 1u);
            atomicAdd(&cnt[(unsigned)c.z >> 8], 1u);
            atomicAdd(&cnt[(unsigned)c.w >> 8], 1u);
        } else {
            for (int k = e; k < end; ++k) atomicAdd(&cnt[(unsigned)col[k] >> 8], 1u);
        }
    }
    __syncthreads();
    for (int b = threadIdx.x; b < NBUCKETS; b += THREADS)
        H[(size_t)b * NBH + blockIdx.x] = cnt[b];
}

// Scan stage 1: per-chunk sums (chunk = 4096 = 256 threads x 16).
__global__ void k_chunksum(const unsigned* __restrict__ a, unsigned* __restrict__ bsum,
                           int L) {
    __shared__ unsigned s[THREADS];
    int t = threadIdx.x;
    int base = blockIdx.x * SCHUNK + t * 16;
    unsigned acc = 0;
    for (int k = 0; k < 16; ++k) {
        int idx = base + k;
        if (idx < L) acc += a[idx];
    }
    s[t] = acc;
    __syncthreads();
    for (int o = THREADS / 2; o > 0; o >>= 1) {
        if (t < o) s[t] += s[t + o];
        __syncthreads();
    }
    if (t == 0) bsum[blockIdx.x] = s[0];
}

// Scan stage 2: single-block exclusive scan of chunk sums (nb <= 256).
__global__ void k_scanblocks(unsigned* __restrict__ bsum, int nb) {
    __shared__ unsigned s[THREADS];
    int t = threadIdx.x;
    unsigned v = (t < nb) ? bsum[t] : 0;
    s[t] = v;
    __syncthreads();
    for (int o = 1; o < THREADS; o <<= 1) {
        unsigned x = (t >= o) ? s[t - o] : 0;
        __syncthreads();
        s[t] += x;
        __syncthreads();
    }
    if (t < nb) bsum[t] = s[t] - v;  // exclusive
}

// Scan stage 3: in-place exclusive scan within each chunk + chunk offset.
__global__ void k_scanchunk(unsigned* __restrict__ a, const unsigned* __restrict__ bsum,
                            int L) {
    __shared__ unsigned s[THREADS];
    int t = threadIdx.x;
    int base = blockIdx.x * SCHUNK + t * 16;
    unsigned v[16];
    unsigned acc = 0;
    for (int k = 0; k < 16; ++k) {
        int idx = base + k;
        v[k] = (idx < L) ? a[idx] : 0;
        acc += v[k];
    }
    s[t] = acc;
    __syncthreads();
    for (int o = 1; o < THREADS; o <<= 1) {
        unsigned x = (t >= o) ? s[t - o] : 0;
        __syncthreads();
        s[t] += x;
        __syncthreads();
    }
    unsigned off = bsum[blockIdx.x] + s[t] - acc;  // exclusive for this thread's run
    for (int k = 0; k < 16; ++k) {
        int idx = base + k;
        if (idx < L) a[idx] = off;
        off += v[k];
    }
}

// Scatter edges into bucket-grouped packed array using scanned cursors.
__global__ void k_scatter(const int* __restrict__ row, const int* __restrict__ col,
                          const unsigned* __restrict__ Hscan, unsigned* __restrict__ packed,
                          int E, int NBH, int NBUCKETS) {
    __shared__ unsigned cur[1024];
    for (int b = threadIdx.x; b < NBUCKETS; b += THREADS)
        cur[b] = Hscan[(size_t)b * NBH + blockIdx.x];
    __syncthreads();
    int base = blockIdx.x * EPB;
    int end = min(base + EPB, E);
    for (int e = base + threadIdx.x * 4; e < end; e += THREADS * 4) {
        if (e + 3 < end) {
            int4 c = reinterpret_cast<const int4*>(col + e)[0];
            int4 r = reinterpret_cast<const int4*>(row + e)[0];
            unsigned p0 = atomicAdd(&cur[(unsigned)c.x >> 8], 1u);
            unsigned p1 = atomicAdd(&cur[(unsigned)c.y >> 8], 1u);
            unsigned p2 = atomicAdd(&cur[(unsigned)c.z >> 8], 1u);
            unsigned p3 = atomicAdd(&cur[(unsigned)c.w >> 8], 1u);
            packed[p0] = ((unsigned)r.x << 8) | ((unsigned)c.x & 255u);
            packed[p1] = ((unsigned)r.y << 8) | ((unsigned)c.y & 255u);
            packed[p2] = ((unsigned)r.z << 8) | ((unsigned)c.z & 255u);
            packed[p3] = ((unsigned)r.w << 8) | ((unsigned)c.w & 255u);
        } else {
            for (int k = e; k < end; ++k) {
                unsigned c = (unsigned)col[k];
                unsigned p = atomicAdd(&cur[c >> 8], 1u);
                packed[p] = ((unsigned)row[k] << 8) | (c & 255u);
            }
        }
    }
}

// Per-bucket in-degree via LDS counters (one block per bucket).
__global__ void k_deg(const unsigned* __restrict__ packed, const unsigned* __restrict__ Hscan,
                      int* __restrict__ deg, int E, int NBH, int N, int NBUCKETS) {
    __shared__ unsigned cnt[THREADS];
    int b = blockIdx.x;
    int t = threadIdx.x;
    cnt[t] = 0;
    __syncthreads();
    unsigned s0 = Hscan[(size_t)b * NBH];
    unsigned s1 = (b + 1 < NBUCKETS) ? Hscan[(size_t)(b + 1) * NBH] : (unsigned)E;
    for (unsigned i = s0 + t; i < s1; i += THREADS)
        atomicAdd(&cnt[packed[i] & 255u], 1u);
    __syncthreads();
    int v = (b << 8) + t;
    if (v < N) deg[v] = (int)cnt[t];
}

// Per-node: dinv = rsqrt(deg+1), xs = dinv*x.
__global__ void k_node1(const float* __restrict__ x, const int* __restrict__ deg,
                        float* __restrict__ dinv, float* __restrict__ xs, int N) {
    int v = blockIdx.x * blockDim.x + threadIdx.x;
    if (v < N) {
        float di = rsqrtf((float)deg[v] + 1.0f);
        dinv[v] = di;
        xs[v] = di * x[v];
    }
}

// Layer 1: per-bucket LDS accumulate of xs[row], then fused 16-unit MLP collapse.
__global__ void k_l1(const unsigned* __restrict__ packed, const unsigned* __restrict__ Hscan,
                     const float* __restrict__ xs, const float* __restrict__ dinv,
                     const float* __restrict__ W1, const float* __restrict__ b1,
                     const float* __restrict__ W2,
                     float* __restrict__ gs, int E, int NBH, int N, int NBUCKETS) {
    __shared__ float acc[THREADS];
    int b = blockIdx.x;
    int t = threadIdx.x;
    acc[t] = 0.0f;
    __syncthreads();
    unsigned s0 = Hscan[(size_t)b * NBH];
    unsigned s1 = (b + 1 < NBUCKETS) ? Hscan[(size_t)(b + 1) * NBH] : (unsigned)E;
    for (unsigned i = s0 + t; i < s1; i += THREADS) {
        unsigned p = packed[i];
        atomicAdd(&acc[p & 255u], xs[p >> 8]);
    }
    __syncthreads();
    int v = (b << 8) + t;
    if (v < N) {
        float di = dinv[v];
        float tt = di * (acc[t] + xs[v]);  // + self-loop
        float g = 0.0f;
#pragma unroll
        for (int j = 0; j < 16; ++j) {
            float y = fmaxf(fmaf(W1[j], tt, b1[j]), 0.0f);
            g = fmaf(W2[2 * j] - W2[2 * j + 1], y, g);
        }
        gs[v] = di * g;
    }
}

// Layer 2: same accumulation over gs + sigmoid epilogue -> (p0, 1-p0).
__global__ void k_l2(const unsigned* __restrict__ packed, const unsigned* __restrict__ Hscan,
                     const float* __restrict__ gs, const float* __restrict__ dinv,
                     const float* __restrict__ b2,
                     float* __restrict__ out, int E, int NBH, int N, int NBUCKETS) {
    __shared__ float acc[THREADS];
    int b = blockIdx.x;
    int t = threadIdx.x;
    acc[t] = 0.0f;
    __syncthreads();
    unsigned s0 = Hscan[(size_t)b * NBH];
    unsigned s1 = (b + 1 < NBUCKETS) ? Hscan[(size_t)(b + 1) * NBH] : (unsigned)E;
    for (unsigned i = s0 + t; i < s1; i += THREADS) {
        unsigned p = packed[i];
        atomicAdd(&acc[p & 255u], gs[p >> 8]);
    }
    __syncthreads();
    int v = (b << 8) + t;
    if (v < N) {
        float diff = dinv[v] * (acc[t] + gs[v]) + (b2[0] - b2[1]);
        float p0 = 1.0f / (1.0f + __expf(-diff));
        float2 o;
        o.x = p0;
        o.y = 1.0f - p0;
        reinterpret_cast<float2*>(out)[v] = o;
    }
}

// ============================ fallback path (R2) ============================
__global__ void k_zero_f(float* __restrict__ p, int n) {
    int i = blockIdx.x * blockDim.x + threadIdx.x;
    int v = i * 4;
    if (v + 3 < n) {
        reinterpret_cast<float4*>(p + v)[0] = make_float4(0.f, 0.f, 0.f, 0.f);
    } else {
        for (; v < n; ++v) p[v] = 0.0f;
    }
}
__global__ void k_deg_f(const int* __restrict__ col, float* __restrict__ deg, int E) {
    int i = blockIdx.x * blockDim.x + threadIdx.x;
    int e = i * 4;
    if (e + 3 < E) {
        int4 c = reinterpret_cast<const int4*>(col + e)[0];
        atomicAdd(deg + c.x, 1.0f); atomicAdd(deg + c.y, 1.0f);
        atomicAdd(deg + c.z, 1.0f); atomicAdd(deg + c.w, 1.0f);
    } else {
        for (; e < E; ++e) atomicAdd(deg + col[e], 1.0f);
    }
}
__global__ void k_node1_f(const float* __restrict__ x, float* __restrict__ degdinv,
                          float* __restrict__ xs, int N) {
    int v = blockIdx.x * blockDim.x + threadIdx.x;
    if (v < N) {
        float dinv = rsqrtf(degdinv[v] + 1.0f);
        degdinv[v] = dinv;
        xs[v] = dinv * x[v];
    }
}
__global__ void k_scat_f(const int* __restrict__ row, const int* __restrict__ col,
                         const float* __restrict__ src, float* __restrict__ acc, int E) {
    int i = blockIdx.x * blockDim.x + threadIdx.x;
    int e = i * 4;
    if (e + 3 < E) {
        int4 r = reinterpret_cast<const int4*>(row + e)[0];
        int4 c = reinterpret_cast<const int4*>(col + e)[0];
        float s0 = src[r.x], s1 = src[r.y], s2 = src[r.z], s3 = src[r.w];
        atomicAdd(acc + c.x, s0); atomicAdd(acc + c.y, s1);
        atomicAdd(acc + c.z, s2); atomicAdd(acc + c.w, s3);
    } else {
        for (; e < E; ++e) atomicAdd(acc + col[e], src[row[e]]);
    }
}
__global__ void k_mlp_f(const float* __restrict__ W1, const float* __restrict__ b1,
                        const float* __restrict__ W2, const float* __restrict__ dinv,
                        float* __restrict__ acc, float* __restrict__ xsgs, int N) {
    int v = blockIdx.x * blockDim.x + threadIdx.x;
    if (v < N) {
        float di = dinv[v];
        float t = di * (acc[v] + xsgs[v]);
        float g = 0.0f;
#pragma unroll
        for (int j = 0; j < 16; ++j) {
            float y = fmaxf(fmaf(W1[j], t, b1[j]), 0.0f);
            g = fmaf(W2[2 * j] - W2[2 * j + 1], y, g);
        }
        xsgs[v] = di * g;
        acc[v] = 0.0f;
    }
}
__global__ void k_out_f(const float* __restrict__ b2, const float* __restrict__ dinv,
                        const float* __restrict__ acc, const float* __restrict__ gs,
                        float* __restrict__ out, int N) {
    int v = blockIdx.x * blockDim.x + threadIdx.x;
    if (v < N) {
        float diff = dinv[v] * (acc[v] + gs[v]) + (b2[0] - b2[1]);
        float p0 = 1.0f / (1.0f + __expf(-diff));
        float2 o; o.x = p0; o.y = 1.0f - p0;
        reinterpret_cast<float2*>(out)[v] = o;
    }
}

extern "C" void kernel_launch(void* const* d_in, const int* in_sizes, int n_in,
                              void* d_out, int out_size, void* d_ws, size_t ws_size,
                              hipStream_t stream) {
    const float* x  = (const float*)d_in[0];
    const int* edge = (const int*)d_in[1];   // int64 in reference -> int32 in harness
    const float* W1 = (const float*)d_in[2];
    const float* b1 = (const float*)d_in[3];
    const float* W2 = (const float*)d_in[4];
    const float* b2 = (const float*)d_in[5];
    float* out = (float*)d_out;

    const int N = in_sizes[0];
    const int E = in_sizes[1] / 2;
    const int* row = edge;       // sources
    const int* col = edge + E;   // targets

    const int NBUCKETS = (N + 255) >> 8;               // bucket = col >> 8
    const int NBH = (E + EPB - 1) / EPB;               // histogram blocks
    const long long L = (long long)NBUCKETS * NBH;     // scan length
    const int SC = (int)((L + SCHUNK - 1) / SCHUNK);   // scan chunks

    // ws: packed[E] | H[L] | bsum[256] | deg[N] (ints) then dinv|xs|gs (floats)
    const size_t need = ((size_t)E + (size_t)L + 256 + N) * 4 + (size_t)3 * N * 4;

    const int nb = (N + THREADS - 1) / THREADS;

    if (NBUCKETS <= 1024 && N < (1 << 24) && SC <= THREADS && ws_size >= need) {
        unsigned* packed = (unsigned*)d_ws;
        unsigned* H      = packed + E;
        unsigned* bsum   = H + L;
        int* deg         = (int*)(bsum + 256);
        float* dinv      = (float*)(deg + N);
        float* xs        = dinv + N;
        float* gs        = xs + N;

        k_hist      <<<NBH, THREADS, 0, stream>>>(col, H, E, NBH, NBUCKETS);
        k_chunksum  <<<SC, THREADS, 0, stream>>>(H, bsum, (int)L);
        k_scanblocks<<<1, THREADS, 0, stream>>>(bsum, SC);
        k_scanchunk <<<SC, THREADS, 0, stream>>>(H, bsum, (int)L);
        k_scatter   <<<NBH, THREADS, 0, stream>>>(row, col, H, packed, E, NBH, NBUCKETS);
        k_deg       <<<NBUCKETS, THREADS, 0, stream>>>(packed, H, deg, E, NBH, N, NBUCKETS);
        k_node1     <<<nb, THREADS, 0, stream>>>(x, deg, dinv, xs, N);
        k_l1        <<<NBUCKETS, THREADS, 0, stream>>>(packed, H, xs, dinv, W1, b1, W2,
                                                       gs, E, NBH, N, NBUCKETS);
        k_l2        <<<NBUCKETS, THREADS, 0, stream>>>(packed, H, gs, dinv, b2,
                                                       out, E, NBH, N, NBUCKETS);
    } else {
        // fallback: R2 atomic-scatter path
        float* w0 = (float*)d_ws;
        float* w1 = w0 + N;
        float* w2 = w1 + N;
        const int eb = ((E + 3) / 4 + THREADS - 1) / THREADS;
        const int zb = ((2 * N + 3) / 4 + THREADS - 1) / THREADS;
        k_zero_f <<<zb, THREADS, 0, stream>>>(w0, 2 * N);
        k_deg_f  <<<eb, THREADS, 0, stream>>>(col, w0, E);
        k_node1_f<<<nb, THREADS, 0, stream>>>(x, w0, w2, N);
        k_scat_f <<<eb, THREADS, 0, stream>>>(row, col, w2, w1, E);
        k_mlp_f  <<<nb, THREADS, 0, stream>>>(W1, b1, W2, w0, w1, w2, N);
        k_scat_f <<<eb, THREADS, 0, stream>>>(row, col, w2, w1, E);
        k_out_f  <<<nb, THREADS, 0, stream>>>(b2, w0, w1, w2, out, N);
    }
}

// Round 5
// 220.037 us; speedup vs baseline: 3.7599x; 1.0271x over previous
//
#include <hip/hip_runtime.h>

#define THREADS 256
#define EPB 10240        // edges per hist/scatter block
#define SCHUNK 4096      // scan chunk (256 threads x 16 items)
#define CSHIFT 11        // coarse bucket = col >> 11 (width 2048)
#define CMASK 2047u
#define LOCAL_T 1024     // threads for local-sort blocks

// ===================== two-level bucketed-sort path =====================
// pack1 = (row << 11) | (col & 2047)   [requires N < 2^21]
// pack2 = (row << 8)  | (col & 255)    [requires N < 2^24]

// Per-block coarse histogram -> H[cb * NBH + block].
__global__ void k_hist1(const int* __restrict__ col, unsigned* __restrict__ H,
                        int E, int NBH, int NC) {
    __shared__ unsigned cnt[128];
    for (int b = threadIdx.x; b < NC; b += THREADS) cnt[b] = 0;
    __syncthreads();
    int base = blockIdx.x * EPB;
    int end = min(base + EPB, E);
    for (int e = base + threadIdx.x * 4; e < end; e += THREADS * 4) {
        if (e + 3 < end) {
            int4 c = reinterpret_cast<const int4*>(col + e)[0];
            atomicAdd(&cnt[(unsigned)c.x >> CSHIFT], 1u);
            atomicAdd(&cnt[(unsigned)c.y >> CSHIFT], 1u);
            atomicAdd(&cnt[(unsigned)c.z >> CSHIFT], 1u);
            atomicAdd(&cnt[(unsigned)c.w >> CSHIFT], 1u);
        } else {
            for (int k = e; k < end; ++k) atomicAdd(&cnt[(unsigned)col[k] >> CSHIFT], 1u);
        }
    }
    __syncthreads();
    for (int b = threadIdx.x; b < NC; b += THREADS)
        H[(size_t)b * NBH + blockIdx.x] = cnt[b];
}

// Scan stage 1: per-chunk sums.
__global__ void k_chunksum(const unsigned* __restrict__ a, unsigned* __restrict__ bsum,
                           int L) {
    __shared__ unsigned s[THREADS];
    int t = threadIdx.x;
    int base = blockIdx.x * SCHUNK + t * 16;
    unsigned acc = 0;
    for (int k = 0; k < 16; ++k) {
        int idx = base + k;
        if (idx < L) acc += a[idx];
    }
    s[t] = acc;
    __syncthreads();
    for (int o = THREADS / 2; o > 0; o >>= 1) {
        if (t < o) s[t] += s[t + o];
        __syncthreads();
    }
    if (t == 0) bsum[blockIdx.x] = s[0];
}

// Scan stage 2: single-block exclusive scan of chunk sums (nb <= 256).
__global__ void k_scanblocks(unsigned* __restrict__ bsum, int nb) {
    __shared__ unsigned s[THREADS];
    int t = threadIdx.x;
    unsigned v = (t < nb) ? bsum[t] : 0;
    s[t] = v;
    __syncthreads();
    for (int o = 1; o < THREADS; o <<= 1) {
        unsigned x = (t >= o) ? s[t - o] : 0;
        __syncthreads();
        s[t] += x;
        __syncthreads();
    }
    if (t < nb) bsum[t] = s[t] - v;  // exclusive
}

// Scan stage 3: in-place exclusive scan within each chunk + chunk offset.
__global__ void k_scanchunk(unsigned* __restrict__ a, const unsigned* __restrict__ bsum,
                            int L) {
    __shared__ unsigned s[THREADS];
    int t = threadIdx.x;
    int base = blockIdx.x * SCHUNK + t * 16;
    unsigned v[16];
    unsigned acc = 0;
    for (int k = 0; k < 16; ++k) {
        int idx = base + k;
        v[k] = (idx < L) ? a[idx] : 0;
        acc += v[k];
    }
    s[t] = acc;
    __syncthreads();
    for (int o = 1; o < THREADS; o <<= 1) {
        unsigned x = (t >= o) ? s[t - o] : 0;
        __syncthreads();
        s[t] += x;
        __syncthreads();
    }
    unsigned off = bsum[blockIdx.x] + s[t] - acc;
    for (int k = 0; k < 16; ++k) {
        int idx = base + k;
        if (idx < L) a[idx] = off;
        off += v[k];
    }
}

// Coarse scatter: pack1 into coarse-bucket-grouped array. Runs ~83 edges/bucket.
__global__ void k_scatter1(const int* __restrict__ row, const int* __restrict__ col,
                           const unsigned* __restrict__ Hscan, unsigned* __restrict__ pack1,
                           int E, int NBH, int NC) {
    __shared__ unsigned cur[128];
    for (int b = threadIdx.x; b < NC; b += THREADS)
        cur[b] = Hscan[(size_t)b * NBH + blockIdx.x];
    __syncthreads();
    int base = blockIdx.x * EPB;
    int end = min(base + EPB, E);
    for (int e = base + threadIdx.x * 4; e < end; e += THREADS * 4) {
        if (e + 3 < end) {
            int4 c = reinterpret_cast<const int4*>(col + e)[0];
            int4 r = reinterpret_cast<const int4*>(row + e)[0];
            unsigned p0 = atomicAdd(&cur[(unsigned)c.x >> CSHIFT], 1u);
            unsigned p1 = atomicAdd(&cur[(unsigned)c.y >> CSHIFT], 1u);
            unsigned p2 = atomicAdd(&cur[(unsigned)c.z >> CSHIFT], 1u);
            unsigned p3 = atomicAdd(&cur[(unsigned)c.w >> CSHIFT], 1u);
            pack1[p0] = ((unsigned)r.x << CSHIFT) | ((unsigned)c.x & CMASK);
            pack1[p1] = ((unsigned)r.y << CSHIFT) | ((unsigned)c.y & CMASK);
            pack1[p2] = ((unsigned)r.z << CSHIFT) | ((unsigned)c.z & CMASK);
            pack1[p3] = ((unsigned)r.w << CSHIFT) | ((unsigned)c.w & CMASK);
        } else {
            for (int k = e; k < end; ++k) {
                unsigned c = (unsigned)col[k];
                unsigned p = atomicAdd(&cur[c >> CSHIFT], 1u);
                pack1[p] = ((unsigned)row[k] << CSHIFT) | (c & CMASK);
            }
        }
    }
}

// Local sort within one coarse bucket (one block per coarse bucket):
//   sweep 1: fine histogram (8 buckets) + per-node degree (2048 LDS counters)
//   sweep 2: scatter to pack2 order (single-writer region -> full-line writeback)
//   tail:    deg -> dinv, xs; emit fine-bucket starts Fstart[c*8 + f].
__global__ void k_local(const unsigned* __restrict__ pack1, const unsigned* __restrict__ Hscan,
                        const float* __restrict__ x,
                        unsigned* __restrict__ pack2, unsigned* __restrict__ Fstart,
                        float* __restrict__ dinv, float* __restrict__ xs,
                        int E, int NBH, int N, int NC) {
    __shared__ unsigned fcnt[8], fbase[8], cur[8];
    __shared__ unsigned dcnt[2048];
    int c = blockIdx.x;
    int t = threadIdx.x;
    for (int i = t; i < 2048; i += LOCAL_T) dcnt[i] = 0;
    if (t < 8) fcnt[t] = 0;
    __syncthreads();
    unsigned s0 = Hscan[(size_t)c * NBH];
    unsigned s1 = (c + 1 < NC) ? Hscan[(size_t)(c + 1) * NBH] : (unsigned)E;
    for (unsigned i = s0 + t; i < s1; i += LOCAL_T) {
        unsigned cl = pack1[i] & CMASK;
        atomicAdd(&dcnt[cl], 1u);
        atomicAdd(&fcnt[cl >> 8], 1u);
    }
    __syncthreads();
    if (t == 0) {
        unsigned run = s0;
        for (int f = 0; f < 8; ++f) { fbase[f] = run; cur[f] = run; run += fcnt[f]; }
    }
    __syncthreads();
    if (t < 8) Fstart[c * 8 + t] = fbase[t];
    for (unsigned i = s0 + t; i < s1; i += LOCAL_T) {
        unsigned p = pack1[i];
        unsigned f = (p & CMASK) >> 8;
        unsigned pos = atomicAdd(&cur[f], 1u);
        pack2[pos] = ((p >> CSHIFT) << 8) | (p & 255u);
    }
    for (int vl = t; vl < 2048; vl += LOCAL_T) {
        int v = (c << CSHIFT) + vl;
        if (v < N) {
            float di = rsqrtf((float)dcnt[vl] + 1.0f);
            dinv[v] = di;
            xs[v] = di * x[v];
        }
    }
}

// Layer 1: per-fine-bucket LDS accumulate of xs[row] + fused MLP collapse.
__global__ void k_l1(const unsigned* __restrict__ pack2, const unsigned* __restrict__ Fstart,
                     const float* __restrict__ xs, const float* __restrict__ dinv,
                     const float* __restrict__ W1, const float* __restrict__ b1,
                     const float* __restrict__ W2,
                     float* __restrict__ gs, int E, int N, int NF) {
    __shared__ float acc[THREADS];
    int b = blockIdx.x;
    int t = threadIdx.x;
    acc[t] = 0.0f;
    __syncthreads();
    unsigned s0 = Fstart[b];
    unsigned s1 = (b + 1 < NF) ? Fstart[b + 1] : (unsigned)E;
    for (unsigned i = s0 + t; i < s1; i += THREADS) {
        unsigned p = pack2[i];
        atomicAdd(&acc[p & 255u], xs[p >> 8]);
    }
    __syncthreads();
    int v = (b << 8) + t;
    if (v < N) {
        float di = dinv[v];
        float tt = di * (acc[t] + xs[v]);  // + self-loop
        float g = 0.0f;
#pragma unroll
        for (int j = 0; j < 16; ++j) {
            float y = fmaxf(fmaf(W1[j], tt, b1[j]), 0.0f);
            g = fmaf(W2[2 * j] - W2[2 * j + 1], y, g);
        }
        gs[v] = di * g;
    }
}

// Layer 2: same accumulation over gs + sigmoid epilogue -> (p0, 1-p0).
__global__ void k_l2(const unsigned* __restrict__ pack2, const unsigned* __restrict__ Fstart,
                     const float* __restrict__ gs, const float* __restrict__ dinv,
                     const float* __restrict__ b2,
                     float* __restrict__ out, int E, int N, int NF) {
    __shared__ float acc[THREADS];
    int b = blockIdx.x;
    int t = threadIdx.x;
    acc[t] = 0.0f;
    __syncthreads();
    unsigned s0 = Fstart[b];
    unsigned s1 = (b + 1 < NF) ? Fstart[b + 1] : (unsigned)E;
    for (unsigned i = s0 + t; i < s1; i += THREADS) {
        unsigned p = pack2[i];
        atomicAdd(&acc[p & 255u], gs[p >> 8]);
    }
    __syncthreads();
    int v = (b << 8) + t;
    if (v < N) {
        float diff = dinv[v] * (acc[t] + gs[v]) + (b2[0] - b2[1]);
        float p0 = 1.0f / (1.0f + __expf(-diff));
        float2 o;
        o.x = p0;
        o.y = 1.0f - p0;
        reinterpret_cast<float2*>(out)[v] = o;
    }
}

// ============================ fallback path (R2) ============================
__global__ void k_zero_f(float* __restrict__ p, int n) {
    int i = blockIdx.x * blockDim.x + threadIdx.x;
    int v = i * 4;
    if (v + 3 < n) {
        reinterpret_cast<float4*>(p + v)[0] = make_float4(0.f, 0.f, 0.f, 0.f);
    } else {
        for (; v < n; ++v) p[v] = 0.0f;
    }
}
__global__ void k_deg_f(const int* __restrict__ col, float* __restrict__ deg, int E) {
    int i = blockIdx.x * blockDim.x + threadIdx.x;
    int e = i * 4;
    if (e + 3 < E) {
        int4 c = reinterpret_cast<const int4*>(col + e)[0];
        atomicAdd(deg + c.x, 1.0f); atomicAdd(deg + c.y, 1.0f);
        atomicAdd(deg + c.z, 1.0f); atomicAdd(deg + c.w, 1.0f);
    } else {
        for (; e < E; ++e) atomicAdd(deg + col[e], 1.0f);
    }
}
__global__ void k_node1_f(const float* __restrict__ x, float* __restrict__ degdinv,
                          float* __restrict__ xs, int N) {
    int v = blockIdx.x * blockDim.x + threadIdx.x;
    if (v < N) {
        float dinv = rsqrtf(degdinv[v] + 1.0f);
        degdinv[v] = dinv;
        xs[v] = dinv * x[v];
    }
}
__global__ void k_scat_f(const int* __restrict__ row, const int* __restrict__ col,
                         const float* __restrict__ src, float* __restrict__ acc, int E) {
    int i = blockIdx.x * blockDim.x + threadIdx.x;
    int e = i * 4;
    if (e + 3 < E) {
        int4 r = reinterpret_cast<const int4*>(row + e)[0];
        int4 c = reinterpret_cast<const int4*>(col + e)[0];
        float s0 = src[r.x], s1 = src[r.y], s2 = src[r.z], s3 = src[r.w];
        atomicAdd(acc + c.x, s0); atomicAdd(acc + c.y, s1);
        atomicAdd(acc + c.z, s2); atomicAdd(acc + c.w, s3);
    } else {
        for (; e < E; ++e) atomicAdd(acc + col[e], src[row[e]]);
    }
}
__global__ void k_mlp_f(const float* __restrict__ W1, const float* __restrict__ b1,
                        const float* __restrict__ W2, const float* __restrict__ dinv,
                        float* __restrict__ acc, float* __restrict__ xsgs, int N) {
    int v = blockIdx.x * blockDim.x + threadIdx.x;
    if (v < N) {
        float di = dinv[v];
        float t = di * (acc[v] + xsgs[v]);
        float g = 0.0f;
#pragma unroll
        for (int j = 0; j < 16; ++j) {
            float y = fmaxf(fmaf(W1[j], t, b1[j]), 0.0f);
            g = fmaf(W2[2 * j] - W2[2 * j + 1], y, g);
        }
        xsgs[v] = di * g;
        acc[v] = 0.0f;
    }
}
__global__ void k_out_f(const float* __restrict__ b2, const float* __restrict__ dinv,
                        const float* __restrict__ acc, const float* __restrict__ gs,
                        float* __restrict__ out, int N) {
    int v = blockIdx.x * blockDim.x + threadIdx.x;
    if (v < N) {
        float diff = dinv[v] * (acc[v] + gs[v]) + (b2[0] - b2[1]);
        float p0 = 1.0f / (1.0f + __expf(-diff));
        float2 o; o.x = p0; o.y = 1.0f - p0;
        reinterpret_cast<float2*>(out)[v] = o;
    }
}

extern "C" void kernel_launch(void* const* d_in, const int* in_sizes, int n_in,
                              void* d_out, int out_size, void* d_ws, size_t ws_size,
                              hipStream_t stream) {
    const float* x  = (const float*)d_in[0];
    const int* edge = (const int*)d_in[1];   // int64 in reference -> int32 in harness
    const float* W1 = (const float*)d_in[2];
    const float* b1 = (const float*)d_in[3];
    const float* W2 = (const float*)d_in[4];
    const float* b2 = (const float*)d_in[5];
    float* out = (float*)d_out;

    const int N = in_sizes[0];
    const int E = in_sizes[1] / 2;
    const int* row = edge;       // sources
    const int* col = edge + E;   // targets

    const int NC  = (N + 2047) >> CSHIFT;              // coarse buckets
    const int NF  = NC * 8;                            // fine bucket slots
    const int NB9 = (N + 255) >> 8;                    // l1/l2 grid (per 256 nodes)
    const int NBH = (E + EPB - 1) / EPB;               // hist/scatter blocks
    const long long L = (long long)NC * NBH;           // scan length
    const int SC = (int)((L + SCHUNK - 1) / SCHUNK);   // scan chunks

    // ws (ints): pack1[E] | pack2[E] | H[L] | bsum[256] | Fstart[NF]
    // ws (floats): dinv[N] | xs[N] | gs[N]
    const size_t need = ((size_t)2 * E + (size_t)L + 256 + NF) * 4 + (size_t)3 * N * 4;

    const int nb = (N + THREADS - 1) / THREADS;

    if (NC <= 128 && N < (1 << 21) && SC <= THREADS && ws_size >= need) {
        unsigned* pack1  = (unsigned*)d_ws;
        unsigned* pack2  = pack1 + E;
        unsigned* H      = pack2 + E;
        unsigned* bsum   = H + L;
        unsigned* Fstart = bsum + 256;
        float* dinv      = (float*)(Fstart + NF);
        float* xs        = dinv + N;
        float* gs        = xs + N;

        k_hist1     <<<NBH, THREADS, 0, stream>>>(col, H, E, NBH, NC);
        k_chunksum  <<<SC, THREADS, 0, stream>>>(H, bsum, (int)L);
        k_scanblocks<<<1, THREADS, 0, stream>>>(bsum, SC);
        k_scanchunk <<<SC, THREADS, 0, stream>>>(H, bsum, (int)L);
        k_scatter1  <<<NBH, THREADS, 0, stream>>>(row, col, H, pack1, E, NBH, NC);
        k_local     <<<NC, LOCAL_T, 0, stream>>>(pack1, H, x, pack2, Fstart,
                                                 dinv, xs, E, NBH, N, NC);
        k_l1        <<<NB9, THREADS, 0, stream>>>(pack2, Fstart, xs, dinv, W1, b1, W2,
                                                  gs, E, N, NF);
        k_l2        <<<NB9, THREADS, 0, stream>>>(pack2, Fstart, gs, dinv, b2,
                                                  out, E, N, NF);
    } else {
        // fallback: R2 atomic-scatter path
        float* w0 = (float*)d_ws;
        float* w1 = w0 + N;
        float* w2 = w1 + N;
        const int eb = ((E + 3) / 4 + THREADS - 1) / THREADS;
        const int zb = ((2 * N + 3) / 4 + THREADS - 1) / THREADS;
        k_zero_f <<<zb, THREADS, 0, stream>>>(w0, 2 * N);
        k_deg_f  <<<eb, THREADS, 0, stream>>>(col, w0, E);
        k_node1_f<<<nb, THREADS, 0, stream>>>(x, w0, w2, N);
        k_scat_f <<<eb, THREADS, 0, stream>>>(row, col, w2, w1, E);
        k_mlp_f  <<<nb, THREADS, 0, stream>>>(W1, b1, W2, w0, w1, w2, N);
        k_scat_f <<<eb, THREADS, 0, stream>>>(row, col, w2, w1, E);
        k_out_f  <<<nb, THREADS, 0, stream>>>(b2, w0, w1, w2, out, N);
    }
}

// Round 6
// 193.547 us; speedup vs baseline: 4.2745x; 1.1369x over previous
//
#include <hip/hip_runtime.h>

#define THREADS 512      // hist/scatter block size
#define EPB 20480        // edges per hist/scatter block
#define SCHUNK 4096      // scan chunk (256 threads x 16 items)
#define CSHIFT 10        // coarse bucket = col >> 10 (width 1024)
#define CMASK 1023u
#define CW 1024          // bucket width = threads for per-bucket kernels

// ======================= one-level bucketed path =======================
// pack1 = (row << 10) | (col & 1023)   [requires N < 2^22]

// Per-block coarse histogram -> H[cb * NBH + block].
__global__ void k_hist1(const int* __restrict__ col, unsigned* __restrict__ H,
                        int E, int NBH, int NC) {
    __shared__ unsigned cnt[1024];
    for (int b = threadIdx.x; b < NC; b += THREADS) cnt[b] = 0;
    __syncthreads();
    int base = blockIdx.x * EPB;
    int end = min(base + EPB, E);
    for (int e = base + threadIdx.x * 4; e < end; e += THREADS * 4) {
        if (e + 3 < end) {
            int4 c = reinterpret_cast<const int4*>(col + e)[0];
            atomicAdd(&cnt[(unsigned)c.x >> CSHIFT], 1u);
            atomicAdd(&cnt[(unsigned)c.y >> CSHIFT], 1u);
            atomicAdd(&cnt[(unsigned)c.z >> CSHIFT], 1u);
            atomicAdd(&cnt[(unsigned)c.w >> CSHIFT], 1u);
        } else {
            for (int k = e; k < end; ++k) atomicAdd(&cnt[(unsigned)col[k] >> CSHIFT], 1u);
        }
    }
    __syncthreads();
    for (int b = threadIdx.x; b < NC; b += THREADS)
        H[(size_t)b * NBH + blockIdx.x] = cnt[b];
}

// Scan stage 1: per-chunk sums.
__global__ void k_chunksum(const unsigned* __restrict__ a, unsigned* __restrict__ bsum,
                           int L) {
    __shared__ unsigned s[256];
    int t = threadIdx.x;
    int base = blockIdx.x * SCHUNK + t * 16;
    unsigned acc = 0;
    for (int k = 0; k < 16; ++k) {
        int idx = base + k;
        if (idx < L) acc += a[idx];
    }
    s[t] = acc;
    __syncthreads();
    for (int o = 128; o > 0; o >>= 1) {
        if (t < o) s[t] += s[t + o];
        __syncthreads();
    }
    if (t == 0) bsum[blockIdx.x] = s[0];
}

// Scan stage 2: single-block exclusive scan of chunk sums (nb <= 256).
__global__ void k_scanblocks(unsigned* __restrict__ bsum, int nb) {
    __shared__ unsigned s[256];
    int t = threadIdx.x;
    unsigned v = (t < nb) ? bsum[t] : 0;
    s[t] = v;
    __syncthreads();
    for (int o = 1; o < 256; o <<= 1) {
        unsigned x = (t >= o) ? s[t - o] : 0;
        __syncthreads();
        s[t] += x;
        __syncthreads();
    }
    if (t < nb) bsum[t] = s[t] - v;  // exclusive
}

// Scan stage 3: in-place exclusive scan within each chunk + chunk offset.
__global__ void k_scanchunk(unsigned* __restrict__ a, const unsigned* __restrict__ bsum,
                            int L) {
    __shared__ unsigned s[256];
    int t = threadIdx.x;
    int base = blockIdx.x * SCHUNK + t * 16;
    unsigned v[16];
    unsigned acc = 0;
    for (int k = 0; k < 16; ++k) {
        int idx = base + k;
        v[k] = (idx < L) ? a[idx] : 0;
        acc += v[k];
    }
    s[t] = acc;
    __syncthreads();
    for (int o = 1; o < 256; o <<= 1) {
        unsigned x = (t >= o) ? s[t - o] : 0;
        __syncthreads();
        s[t] += x;
        __syncthreads();
    }
    unsigned off = bsum[blockIdx.x] + s[t] - acc;
    for (int k = 0; k < 16; ++k) {
        int idx = base + k;
        if (idx < L) a[idx] = off;
        off += v[k];
    }
}

// Coarse scatter: pack1 into bucket-grouped array (runs ~84 edges = 334 B).
__global__ void k_scatter1(const int* __restrict__ row, const int* __restrict__ col,
                           const unsigned* __restrict__ Hscan, unsigned* __restrict__ pack1,
                           int E, int NBH, int NC) {
    __shared__ unsigned cur[1024];
    for (int b = threadIdx.x; b < NC; b += THREADS)
        cur[b] = Hscan[(size_t)b * NBH + blockIdx.x];
    __syncthreads();
    int base = blockIdx.x * EPB;
    int end = min(base + EPB, E);
    for (int e = base + threadIdx.x * 4; e < end; e += THREADS * 4) {
        if (e + 3 < end) {
            int4 c = reinterpret_cast<const int4*>(col + e)[0];
            int4 r = reinterpret_cast<const int4*>(row + e)[0];
            unsigned p0 = atomicAdd(&cur[(unsigned)c.x >> CSHIFT], 1u);
            unsigned p1 = atomicAdd(&cur[(unsigned)c.y >> CSHIFT], 1u);
            unsigned p2 = atomicAdd(&cur[(unsigned)c.z >> CSHIFT], 1u);
            unsigned p3 = atomicAdd(&cur[(unsigned)c.w >> CSHIFT], 1u);
            pack1[p0] = ((unsigned)r.x << CSHIFT) | ((unsigned)c.x & CMASK);
            pack1[p1] = ((unsigned)r.y << CSHIFT) | ((unsigned)c.y & CMASK);
            pack1[p2] = ((unsigned)r.z << CSHIFT) | ((unsigned)c.z & CMASK);
            pack1[p3] = ((unsigned)r.w << CSHIFT) | ((unsigned)c.w & CMASK);
        } else {
            for (int k = e; k < end; ++k) {
                unsigned c = (unsigned)col[k];
                unsigned p = atomicAdd(&cur[c >> CSHIFT], 1u);
                pack1[p] = ((unsigned)row[k] << CSHIFT) | (c & CMASK);
            }
        }
    }
}

// Per-bucket degree via LDS counters; emit dinv = rsqrt(deg+1), xs = dinv*x.
// One block (1024 thr) per coarse bucket; one node per thread.
__global__ void k_deg_local(const unsigned* __restrict__ pack1,
                            const unsigned* __restrict__ Hscan,
                            const float* __restrict__ x,
                            float* __restrict__ dinv, float* __restrict__ xs,
                            int E, int NBH, int N, int NC) {
    __shared__ unsigned dcnt[CW];
    int b = blockIdx.x;
    int t = threadIdx.x;
    dcnt[t] = 0;
    __syncthreads();
    unsigned s0 = Hscan[(size_t)b * NBH];
    unsigned s1 = (b + 1 < NC) ? Hscan[(size_t)(b + 1) * NBH] : (unsigned)E;
    for (unsigned i = s0 + t; i < s1; i += CW)
        atomicAdd(&dcnt[pack1[i] & CMASK], 1u);
    __syncthreads();
    int v = (b << CSHIFT) + t;
    if (v < N) {
        float di = rsqrtf((float)dcnt[t] + 1.0f);
        dinv[v] = di;
        xs[v] = di * x[v];
    }
}

// Layer 1: per-bucket LDS accumulate of xs[row] + fused MLP collapse -> gs.
__global__ void k_l1c(const unsigned* __restrict__ pack1,
                      const unsigned* __restrict__ Hscan,
                      const float* __restrict__ xs, const float* __restrict__ dinv,
                      const float* __restrict__ W1, const float* __restrict__ b1,
                      const float* __restrict__ W2,
                      float* __restrict__ gs, int E, int NBH, int N, int NC) {
    __shared__ float acc[CW];
    int b = blockIdx.x;
    int t = threadIdx.x;
    acc[t] = 0.0f;
    __syncthreads();
    unsigned s0 = Hscan[(size_t)b * NBH];
    unsigned s1 = (b + 1 < NC) ? Hscan[(size_t)(b + 1) * NBH] : (unsigned)E;
    for (unsigned i = s0 + t; i < s1; i += CW) {
        unsigned p = pack1[i];
        atomicAdd(&acc[p & CMASK], xs[p >> CSHIFT]);
    }
    __syncthreads();
    int v = (b << CSHIFT) + t;
    if (v < N) {
        float di = dinv[v];
        float tt = di * (acc[t] + xs[v]);  // + self-loop
        float g = 0.0f;
#pragma unroll
        for (int j = 0; j < 16; ++j) {
            float y = fmaxf(fmaf(W1[j], tt, b1[j]), 0.0f);
            g = fmaf(W2[2 * j] - W2[2 * j + 1], y, g);
        }
        gs[v] = di * g;
    }
}

// Layer 2: same accumulation over gs + sigmoid epilogue -> (p0, 1-p0).
__global__ void k_l2c(const unsigned* __restrict__ pack1,
                      const unsigned* __restrict__ Hscan,
                      const float* __restrict__ gs, const float* __restrict__ dinv,
                      const float* __restrict__ b2,
                      float* __restrict__ out, int E, int NBH, int N, int NC) {
    __shared__ float acc[CW];
    int b = blockIdx.x;
    int t = threadIdx.x;
    acc[t] = 0.0f;
    __syncthreads();
    unsigned s0 = Hscan[(size_t)b * NBH];
    unsigned s1 = (b + 1 < NC) ? Hscan[(size_t)(b + 1) * NBH] : (unsigned)E;
    for (unsigned i = s0 + t; i < s1; i += CW) {
        unsigned p = pack1[i];
        atomicAdd(&acc[p & CMASK], gs[p >> CSHIFT]);
    }
    __syncthreads();
    int v = (b << CSHIFT) + t;
    if (v < N) {
        float diff = dinv[v] * (acc[t] + gs[v]) + (b2[0] - b2[1]);
        float p0 = 1.0f / (1.0f + __expf(-diff));
        float2 o;
        o.x = p0;
        o.y = 1.0f - p0;
        reinterpret_cast<float2*>(out)[v] = o;
    }
}

// ============================ fallback path (R2) ============================
__global__ void k_zero_f(float* __restrict__ p, int n) {
    int i = blockIdx.x * blockDim.x + threadIdx.x;
    int v = i * 4;
    if (v + 3 < n) {
        reinterpret_cast<float4*>(p + v)[0] = make_float4(0.f, 0.f, 0.f, 0.f);
    } else {
        for (; v < n; ++v) p[v] = 0.0f;
    }
}
__global__ void k_deg_f(const int* __restrict__ col, float* __restrict__ deg, int E) {
    int i = blockIdx.x * blockDim.x + threadIdx.x;
    int e = i * 4;
    if (e + 3 < E) {
        int4 c = reinterpret_cast<const int4*>(col + e)[0];
        atomicAdd(deg + c.x, 1.0f); atomicAdd(deg + c.y, 1.0f);
        atomicAdd(deg + c.z, 1.0f); atomicAdd(deg + c.w, 1.0f);
    } else {
        for (; e < E; ++e) atomicAdd(deg + col[e], 1.0f);
    }
}
__global__ void k_node1_f(const float* __restrict__ x, float* __restrict__ degdinv,
                          float* __restrict__ xs, int N) {
    int v = blockIdx.x * blockDim.x + threadIdx.x;
    if (v < N) {
        float dinv = rsqrtf(degdinv[v] + 1.0f);
        degdinv[v] = dinv;
        xs[v] = dinv * x[v];
    }
}
__global__ void k_scat_f(const int* __restrict__ row, const int* __restrict__ col,
                         const float* __restrict__ src, float* __restrict__ acc, int E) {
    int i = blockIdx.x * blockDim.x + threadIdx.x;
    int e = i * 4;
    if (e + 3 < E) {
        int4 r = reinterpret_cast<const int4*>(row + e)[0];
        int4 c = reinterpret_cast<const int4*>(col + e)[0];
        float s0 = src[r.x], s1 = src[r.y], s2 = src[r.z], s3 = src[r.w];
        atomicAdd(acc + c.x, s0); atomicAdd(acc + c.y, s1);
        atomicAdd(acc + c.z, s2); atomicAdd(acc + c.w, s3);
    } else {
        for (; e < E; ++e) atomicAdd(acc + col[e], src[row[e]]);
    }
}
__global__ void k_mlp_f(const float* __restrict__ W1, const float* __restrict__ b1,
                        const float* __restrict__ W2, const float* __restrict__ dinv,
                        float* __restrict__ acc, float* __restrict__ xsgs, int N) {
    int v = blockIdx.x * blockDim.x + threadIdx.x;
    if (v < N) {
        float di = dinv[v];
        float t = di * (acc[v] + xsgs[v]);
        float g = 0.0f;
#pragma unroll
        for (int j = 0; j < 16; ++j) {
            float y = fmaxf(fmaf(W1[j], t, b1[j]), 0.0f);
            g = fmaf(W2[2 * j] - W2[2 * j + 1], y, g);
        }
        xsgs[v] = di * g;
        acc[v] = 0.0f;
    }
}
__global__ void k_out_f(const float* __restrict__ b2, const float* __restrict__ dinv,
                        const float* __restrict__ acc, const float* __restrict__ gs,
                        float* __restrict__ out, int N) {
    int v = blockIdx.x * blockDim.x + threadIdx.x;
    if (v < N) {
        float diff = dinv[v] * (acc[v] + gs[v]) + (b2[0] - b2[1]);
        float p0 = 1.0f / (1.0f + __expf(-diff));
        float2 o; o.x = p0; o.y = 1.0f - p0;
        reinterpret_cast<float2*>(out)[v] = o;
    }
}

extern "C" void kernel_launch(void* const* d_in, const int* in_sizes, int n_in,
                              void* d_out, int out_size, void* d_ws, size_t ws_size,
                              hipStream_t stream) {
    const float* x  = (const float*)d_in[0];
    const int* edge = (const int*)d_in[1];   // int64 in reference -> int32 in harness
    const float* W1 = (const float*)d_in[2];
    const float* b1 = (const float*)d_in[3];
    const float* W2 = (const float*)d_in[4];
    const float* b2 = (const float*)d_in[5];
    float* out = (float*)d_out;

    const int N = in_sizes[0];
    const int E = in_sizes[1] / 2;
    const int* row = edge;       // sources
    const int* col = edge + E;   // targets

    const int NC  = (N + CW - 1) >> CSHIFT;            // coarse buckets (245)
    const int NBH = (E + EPB - 1) / EPB;               // hist/scatter blocks (245)
    const long long L = (long long)NC * NBH;           // scan length (~60k)
    const int SC = (int)((L + SCHUNK - 1) / SCHUNK);   // scan chunks (15)

    // ws (ints): pack1[E] | H[L] | bsum[256]; (floats): dinv[N] | xs[N] | gs[N]
    const size_t need = ((size_t)E + (size_t)L + 256) * 4 + (size_t)3 * N * 4;

    const int nb = (N + 255) / 256;

    if (NC <= 1024 && N < (1 << 22) && SC <= 256 && ws_size >= need) {
        unsigned* pack1 = (unsigned*)d_ws;
        unsigned* H     = pack1 + E;
        unsigned* bsum  = H + L;
        float* dinv     = (float*)(bsum + 256);
        float* xs       = dinv + N;
        float* gs       = xs + N;

        k_hist1     <<<NBH, THREADS, 0, stream>>>(col, H, E, NBH, NC);
        k_chunksum  <<<SC, 256, 0, stream>>>(H, bsum, (int)L);
        k_scanblocks<<<1, 256, 0, stream>>>(bsum, SC);
        k_scanchunk <<<SC, 256, 0, stream>>>(H, bsum, (int)L);
        k_scatter1  <<<NBH, THREADS, 0, stream>>>(row, col, H, pack1, E, NBH, NC);
        k_deg_local <<<NC, CW, 0, stream>>>(pack1, H, x, dinv, xs, E, NBH, N, NC);
        k_l1c       <<<NC, CW, 0, stream>>>(pack1, H, xs, dinv, W1, b1, W2,
                                            gs, E, NBH, N, NC);
        k_l2c       <<<NC, CW, 0, stream>>>(pack1, H, gs, dinv, b2,
                                            out, E, NBH, N, NC);
    } else {
        // fallback: R2 atomic-scatter path
        float* w0 = (float*)d_ws;
        float* w1 = w0 + N;
        float* w2 = w1 + N;
        const int eb = ((E + 3) / 4 + 255) / 256;
        const int zb = ((2 * N + 3) / 4 + 255) / 256;
        k_zero_f <<<zb, 256, 0, stream>>>(w0, 2 * N);
        k_deg_f  <<<eb, 256, 0, stream>>>(col, w0, E);
        k_node1_f<<<nb, 256, 0, stream>>>(x, w0, w2, N);
        k_scat_f <<<eb, 256, 0, stream>>>(row, col, w2, w1, E);
        k_mlp_f  <<<nb, 256, 0, stream>>>(W1, b1, W2, w0, w1, w2, N);
        k_scat_f <<<eb, 256, 0, stream>>>(row, col, w2, w1, E);
        k_out_f  <<<nb, 256, 0, stream>>>(b2, w0, w1, w2, out, N);
    }
}

// Round 7
// 181.181 us; speedup vs baseline: 4.5662x; 1.0683x over previous
//
#include <hip/hip_runtime.h>

#define ST 1024          // sort block threads
#define PT 20            // edges per sort thread
#define EPB (ST * PT)    // 20480 edges per sort block
#define CSHIFT 10        // bucket = col >> 10 (width 1024)
#define CMASK 1023u
#define CW 1024          // bucket width = threads for per-bucket kernels
#define CAP 24576        // slots per bucket (mean 20408, 29 sigma slack)

// ==================== reservation-sort path ====================
// pack1 = (row << 10) | (col & 1023)   [requires N < 2^22]
// bucket b owns pack1[b*CAP .. gcur[b]) after k_sort.

// Init per-bucket global cursors to region bases.
__global__ void k_init(unsigned* __restrict__ gcur, int NC) {
    for (int b = threadIdx.x; b < NC; b += blockDim.x)
        gcur[b] = (unsigned)b * CAP;
}

// One pass over the edge list: LDS mini-hist (col kept in registers),
// one global atomicAdd per (block,bucket) reservation, then place.
__global__ __launch_bounds__(ST) void k_sort(const int* __restrict__ row,
                                             const int* __restrict__ col,
                                             unsigned* __restrict__ gcur,
                                             unsigned* __restrict__ pack1,
                                             int E, int NC) {
    __shared__ unsigned cnt[CW];
    __shared__ unsigned cur[CW];
    int t = threadIdx.x;
    cnt[t] = 0;
    __syncthreads();

    int base = blockIdx.x * EPB;
    int c[PT];

#pragma unroll
    for (int k = 0; k < PT / 4; ++k) {
        int e = base + (k * ST + t) * 4;
        int4 cc;
        if (e + 3 < E) {
            cc = *reinterpret_cast<const int4*>(col + e);
        } else {
            cc.x = (e + 0 < E) ? col[e + 0] : -1;
            cc.y = (e + 1 < E) ? col[e + 1] : -1;
            cc.z = (e + 2 < E) ? col[e + 2] : -1;
            cc.w = (e + 3 < E) ? col[e + 3] : -1;
        }
        c[4 * k + 0] = cc.x; c[4 * k + 1] = cc.y;
        c[4 * k + 2] = cc.z; c[4 * k + 3] = cc.w;
    }
#pragma unroll
    for (int k = 0; k < PT; ++k)
        if (c[k] >= 0) atomicAdd(&cnt[(unsigned)c[k] >> CSHIFT], 1u);
    __syncthreads();

    if (t < NC) cur[t] = atomicAdd(&gcur[t], cnt[t]);  // reserve contiguous run
    __syncthreads();

#pragma unroll
    for (int k = 0; k < PT / 4; ++k) {
        int e = base + (k * ST + t) * 4;
        int4 rr;
        if (e + 3 < E) {
            rr = *reinterpret_cast<const int4*>(row + e);
        } else {
            rr.x = (e + 0 < E) ? row[e + 0] : 0;
            rr.y = (e + 1 < E) ? row[e + 1] : 0;
            rr.z = (e + 2 < E) ? row[e + 2] : 0;
            rr.w = (e + 3 < E) ? row[e + 3] : 0;
        }
        int rl[4] = {rr.x, rr.y, rr.z, rr.w};
#pragma unroll
        for (int j = 0; j < 4; ++j) {
            int cc = c[4 * k + j];
            if (cc >= 0) {
                unsigned b = (unsigned)cc >> CSHIFT;
                unsigned pos = atomicAdd(&cur[b], 1u);
                if (pos < (b + 1u) * CAP)  // overflow guard (29-sigma, never hit)
                    pack1[pos] = ((unsigned)rl[j] << CSHIFT) | ((unsigned)cc & CMASK);
            }
        }
    }
}

// Per-bucket degree via LDS counters; emit dinv = rsqrt(deg+1), xs = dinv*x.
__global__ void k_deg(const unsigned* __restrict__ pack1, const unsigned* __restrict__ gcur,
                      const float* __restrict__ x,
                      float* __restrict__ dinv, float* __restrict__ xs, int N) {
    __shared__ unsigned dcnt[CW];
    int b = blockIdx.x;
    int t = threadIdx.x;
    dcnt[t] = 0;
    __syncthreads();
    unsigned s0 = (unsigned)b * CAP;
    unsigned s1 = min(gcur[b], s0 + CAP);
    unsigned n4 = (s1 - s0) >> 2;
    for (unsigned i = t; i < n4; i += CW) {
        uint4 p = reinterpret_cast<const uint4*>(pack1 + s0)[i];
        atomicAdd(&dcnt[p.x & CMASK], 1u);
        atomicAdd(&dcnt[p.y & CMASK], 1u);
        atomicAdd(&dcnt[p.z & CMASK], 1u);
        atomicAdd(&dcnt[p.w & CMASK], 1u);
    }
    unsigned i = s0 + (n4 << 2) + t;
    if (i < s1) atomicAdd(&dcnt[pack1[i] & CMASK], 1u);
    __syncthreads();
    int v = (b << CSHIFT) + t;
    if (v < N) {
        float di = rsqrtf((float)dcnt[t] + 1.0f);
        dinv[v] = di;
        xs[v] = di * x[v];
    }
}

// Layer 1: per-bucket LDS accumulate of xs[row] + fused MLP collapse -> gs.
__global__ void k_l1(const unsigned* __restrict__ pack1, const unsigned* __restrict__ gcur,
                     const float* __restrict__ xs, const float* __restrict__ dinv,
                     const float* __restrict__ W1, const float* __restrict__ b1,
                     const float* __restrict__ W2,
                     float* __restrict__ gs, int N) {
    __shared__ float acc[CW];
    int b = blockIdx.x;
    int t = threadIdx.x;
    acc[t] = 0.0f;
    __syncthreads();
    unsigned s0 = (unsigned)b * CAP;
    unsigned s1 = min(gcur[b], s0 + CAP);
    unsigned n4 = (s1 - s0) >> 2;
    for (unsigned i = t; i < n4; i += CW) {
        uint4 p = reinterpret_cast<const uint4*>(pack1 + s0)[i];
        float v0 = xs[p.x >> CSHIFT];
        float v1 = xs[p.y >> CSHIFT];
        float v2 = xs[p.z >> CSHIFT];
        float v3 = xs[p.w >> CSHIFT];
        atomicAdd(&acc[p.x & CMASK], v0);
        atomicAdd(&acc[p.y & CMASK], v1);
        atomicAdd(&acc[p.z & CMASK], v2);
        atomicAdd(&acc[p.w & CMASK], v3);
    }
    unsigned i = s0 + (n4 << 2) + t;
    if (i < s1) {
        unsigned p = pack1[i];
        atomicAdd(&acc[p & CMASK], xs[p >> CSHIFT]);
    }
    __syncthreads();
    int v = (b << CSHIFT) + t;
    if (v < N) {
        float di = dinv[v];
        float tt = di * (acc[t] + xs[v]);  // + self-loop
        float g = 0.0f;
#pragma unroll
        for (int j = 0; j < 16; ++j) {
            float y = fmaxf(fmaf(W1[j], tt, b1[j]), 0.0f);
            g = fmaf(W2[2 * j] - W2[2 * j + 1], y, g);
        }
        gs[v] = di * g;
    }
}

// Layer 2: same accumulation over gs + sigmoid epilogue -> (p0, 1-p0).
__global__ void k_l2(const unsigned* __restrict__ pack1, const unsigned* __restrict__ gcur,
                     const float* __restrict__ gs, const float* __restrict__ dinv,
                     const float* __restrict__ b2,
                     float* __restrict__ out, int N) {
    __shared__ float acc[CW];
    int b = blockIdx.x;
    int t = threadIdx.x;
    acc[t] = 0.0f;
    __syncthreads();
    unsigned s0 = (unsigned)b * CAP;
    unsigned s1 = min(gcur[b], s0 + CAP);
    unsigned n4 = (s1 - s0) >> 2;
    for (unsigned i = t; i < n4; i += CW) {
        uint4 p = reinterpret_cast<const uint4*>(pack1 + s0)[i];
        float v0 = gs[p.x >> CSHIFT];
        float v1 = gs[p.y >> CSHIFT];
        float v2 = gs[p.z >> CSHIFT];
        float v3 = gs[p.w >> CSHIFT];
        atomicAdd(&acc[p.x & CMASK], v0);
        atomicAdd(&acc[p.y & CMASK], v1);
        atomicAdd(&acc[p.z & CMASK], v2);
        atomicAdd(&acc[p.w & CMASK], v3);
    }
    unsigned i = s0 + (n4 << 2) + t;
    if (i < s1) {
        unsigned p = pack1[i];
        atomicAdd(&acc[p & CMASK], gs[p >> CSHIFT]);
    }
    __syncthreads();
    int v = (b << CSHIFT) + t;
    if (v < N) {
        float diff = dinv[v] * (acc[t] + gs[v]) + (b2[0] - b2[1]);
        float p0 = 1.0f / (1.0f + __expf(-diff));
        float2 o;
        o.x = p0;
        o.y = 1.0f - p0;
        reinterpret_cast<float2*>(out)[v] = o;
    }
}

// ==================== fallback path (R2, any sizes) ====================
__global__ void k_zero_f(float* __restrict__ p, int n) {
    int i = blockIdx.x * blockDim.x + threadIdx.x;
    int v = i * 4;
    if (v + 3 < n) {
        reinterpret_cast<float4*>(p + v)[0] = make_float4(0.f, 0.f, 0.f, 0.f);
    } else {
        for (; v < n; ++v) p[v] = 0.0f;
    }
}
__global__ void k_deg_f(const int* __restrict__ col, float* __restrict__ deg, int E) {
    int i = blockIdx.x * blockDim.x + threadIdx.x;
    int e = i * 4;
    if (e + 3 < E) {
        int4 c = reinterpret_cast<const int4*>(col + e)[0];
        atomicAdd(deg + c.x, 1.0f); atomicAdd(deg + c.y, 1.0f);
        atomicAdd(deg + c.z, 1.0f); atomicAdd(deg + c.w, 1.0f);
    } else {
        for (; e < E; ++e) atomicAdd(deg + col[e], 1.0f);
    }
}
__global__ void k_node1_f(const float* __restrict__ x, float* __restrict__ degdinv,
                          float* __restrict__ xs, int N) {
    int v = blockIdx.x * blockDim.x + threadIdx.x;
    if (v < N) {
        float dinv = rsqrtf(degdinv[v] + 1.0f);
        degdinv[v] = dinv;
        xs[v] = dinv * x[v];
    }
}
__global__ void k_scat_f(const int* __restrict__ row, const int* __restrict__ col,
                         const float* __restrict__ src, float* __restrict__ acc, int E) {
    int i = blockIdx.x * blockDim.x + threadIdx.x;
    int e = i * 4;
    if (e + 3 < E) {
        int4 r = reinterpret_cast<const int4*>(row + e)[0];
        int4 c = reinterpret_cast<const int4*>(col + e)[0];
        float s0 = src[r.x], s1 = src[r.y], s2 = src[r.z], s3 = src[r.w];
        atomicAdd(acc + c.x, s0); atomicAdd(acc + c.y, s1);
        atomicAdd(acc + c.z, s2); atomicAdd(acc + c.w, s3);
    } else {
        for (; e < E; ++e) atomicAdd(acc + col[e], src[row[e]]);
    }
}
__global__ void k_mlp_f(const float* __restrict__ W1, const float* __restrict__ b1,
                        const float* __restrict__ W2, const float* __restrict__ dinv,
                        float* __restrict__ acc, float* __restrict__ xsgs, int N) {
    int v = blockIdx.x * blockDim.x + threadIdx.x;
    if (v < N) {
        float di = dinv[v];
        float t = di * (acc[v] + xsgs[v]);
        float g = 0.0f;
#pragma unroll
        for (int j = 0; j < 16; ++j) {
            float y = fmaxf(fmaf(W1[j], t, b1[j]), 0.0f);
            g = fmaf(W2[2 * j] - W2[2 * j + 1], y, g);
        }
        xsgs[v] = di * g;
        acc[v] = 0.0f;
    }
}
__global__ void k_out_f(const float* __restrict__ b2, const float* __restrict__ dinv,
                        const float* __restrict__ acc, const float* __restrict__ gs,
                        float* __restrict__ out, int N) {
    int v = blockIdx.x * blockDim.x + threadIdx.x;
    if (v < N) {
        float diff = dinv[v] * (acc[v] + gs[v]) + (b2[0] - b2[1]);
        float p0 = 1.0f / (1.0f + __expf(-diff));
        float2 o; o.x = p0; o.y = 1.0f - p0;
        reinterpret_cast<float2*>(out)[v] = o;
    }
}

extern "C" void kernel_launch(void* const* d_in, const int* in_sizes, int n_in,
                              void* d_out, int out_size, void* d_ws, size_t ws_size,
                              hipStream_t stream) {
    const float* x  = (const float*)d_in[0];
    const int* edge = (const int*)d_in[1];   // int64 in reference -> int32 in harness
    const float* W1 = (const float*)d_in[2];
    const float* b1 = (const float*)d_in[3];
    const float* W2 = (const float*)d_in[4];
    const float* b2 = (const float*)d_in[5];
    float* out = (float*)d_out;

    const int N = in_sizes[0];
    const int E = in_sizes[1] / 2;
    const int* row = edge;       // sources
    const int* col = edge + E;   // targets

    const int NC  = (N + CW - 1) >> CSHIFT;            // buckets (245)
    const int NBS = (E + EPB - 1) / EPB;               // sort blocks (245)

    // Capacity check: mean load E/NC plus 8-sigma must fit CAP.
    const double mean = (double)E / NC;
    const double slack = mean + 8.0 * __builtin_sqrt(mean);
    // ws (ints): pack1[NC*CAP] | gcur[NC]; (floats): dinv[N] | xs[N] | gs[N]
    const size_t need = ((size_t)NC * CAP + NC) * 4 + (size_t)3 * N * 4;

    const int nb = (N + 255) / 256;

    if (NC <= 1024 && N < (1 << 22) && slack < CAP && ws_size >= need) {
        unsigned* pack1 = (unsigned*)d_ws;
        unsigned* gcur  = pack1 + (size_t)NC * CAP;
        float* dinv     = (float*)(gcur + NC);
        float* xs       = dinv + N;
        float* gs       = xs + N;

        k_init<<<1, 256, 0, stream>>>(gcur, NC);
        k_sort<<<NBS, ST, 0, stream>>>(row, col, gcur, pack1, E, NC);
        k_deg <<<NC, CW, 0, stream>>>(pack1, gcur, x, dinv, xs, N);
        k_l1  <<<NC, CW, 0, stream>>>(pack1, gcur, xs, dinv, W1, b1, W2, gs, N);
        k_l2  <<<NC, CW, 0, stream>>>(pack1, gcur, gs, dinv, b2, out, N);
    } else {
        // fallback: R2 atomic-scatter path
        float* w0 = (float*)d_ws;
        float* w1 = w0 + N;
        float* w2 = w1 + N;
        const int eb = ((E + 3) / 4 + 255) / 256;
        const int zb = ((2 * N + 3) / 4 + 255) / 256;
        k_zero_f <<<zb, 256, 0, stream>>>(w0, 2 * N);
        k_deg_f  <<<eb, 256, 0, stream>>>(col, w0, E);
        k_node1_f<<<nb, 256, 0, stream>>>(x, w0, w2, N);
        k_scat_f <<<eb, 256, 0, stream>>>(row, col, w2, w1, E);
        k_mlp_f  <<<nb, 256, 0, stream>>>(W1, b1, W2, w0, w1, w2, N);
        k_scat_f <<<eb, 256, 0, stream>>>(row, col, w2, w1, E);
        k_out_f  <<<nb, 256, 0, stream>>>(b2, w0, w1, w2, out, N);
    }
}